// Round 1
// 1049.052 us; speedup vs baseline: 1.0216x; 1.0216x over previous
//
#include <hip/hip_runtime.h>

#define TOKENS 4096
#define DDIM   2048
#define HDIM   1024
#define NEXP   8
#define GK     2048
#define GN     2048

typedef __bf16 bf16_t;
typedef __bf16 bf16x8 __attribute__((ext_vector_type(8)));
typedef __bf16 bf16x4 __attribute__((ext_vector_type(4)));
typedef float  f32x4  __attribute__((ext_vector_type(4)));

__device__ inline void gld_lds16(const bf16_t* g, bf16_t* l) {
  __builtin_amdgcn_global_load_lds(
      (const __attribute__((address_space(1))) void*)g,
      (__attribute__((address_space(3))) void*)l, 16, 0, 0);
}

#define LGKM0() asm volatile("s_waitcnt lgkmcnt(0)" ::: "memory")
#define VMC(n)  asm volatile("s_waitcnt vmcnt(" #n ")" ::: "memory")
#define BAR()   __builtin_amdgcn_s_barrier()

// ---------------- routing: gate_g (softmax+top2) and gate_f (softmax), fold weight[] ----------------
__global__ __launch_bounds__(256)
void k_routing(const float* __restrict__ vec,
               const float* __restrict__ Wg, const float* __restrict__ bg,
               const float* __restrict__ Wf, const float* __restrict__ bfv,
               const float* __restrict__ wgt,
               float* __restrict__ c0, float* __restrict__ c1)
{
  const int wave = threadIdx.x >> 6;
  const int lane = threadIdx.x & 63;
  const int m = blockIdx.x * 4 + wave;
  const float* v = vec + (size_t)m * DDIM;

  float ag[NEXP], af[NEXP];
#pragma unroll
  for (int e = 0; e < NEXP; ++e) { ag[e] = 0.f; af[e] = 0.f; }

  for (int i = lane; i < HDIM; i += 64) {
    const float xg = v[i];
    const float xf = v[HDIM + i];
    const float4 wg0 = *(const float4*)(Wg + i * NEXP);
    const float4 wg1 = *(const float4*)(Wg + i * NEXP + 4);
    const float4 wf0 = *(const float4*)(Wf + i * NEXP);
    const float4 wf1 = *(const float4*)(Wf + i * NEXP + 4);
    ag[0] += xg * wg0.x; ag[1] += xg * wg0.y; ag[2] += xg * wg0.z; ag[3] += xg * wg0.w;
    ag[4] += xg * wg1.x; ag[5] += xg * wg1.y; ag[6] += xg * wg1.z; ag[7] += xg * wg1.w;
    af[0] += xf * wf0.x; af[1] += xf * wf0.y; af[2] += xf * wf0.z; af[3] += xf * wf0.w;
    af[4] += xf * wf1.x; af[5] += xf * wf1.y; af[6] += xf * wf1.z; af[7] += xf * wf1.w;
  }
#pragma unroll
  for (int e = 0; e < NEXP; ++e) {
#pragma unroll
    for (int off = 32; off >= 1; off >>= 1) {
      ag[e] += __shfl_xor(ag[e], off, 64);
      af[e] += __shfl_xor(af[e], off, 64);
    }
  }
  if (lane == 0) {
    float g[NEXP], f[NEXP];
    float mg = -1e30f, mf = -1e30f;
#pragma unroll
    for (int e = 0; e < NEXP; ++e) {
      g[e] = ag[e] + bg[e]; mg = fmaxf(mg, g[e]);
      f[e] = af[e] + bfv[e]; mf = fmaxf(mf, f[e]);
    }
    float sg = 0.f, sf = 0.f;
#pragma unroll
    for (int e = 0; e < NEXP; ++e) {
      g[e] = expf(g[e] - mg); sg += g[e];
      f[e] = expf(f[e] - mf); sf += f[e];
    }
    const float rg = 1.f / sg, rf = 1.f / sf;
#pragma unroll
    for (int e = 0; e < NEXP; ++e) { g[e] *= rg; f[e] *= rf; }
    int i1 = 0;
#pragma unroll
    for (int e = 1; e < NEXP; ++e) if (g[e] > g[i1]) i1 = e;
    int i2 = (i1 == 0) ? 1 : 0;
#pragma unroll
    for (int e = 0; e < NEXP; ++e) if (e != i1 && g[e] > g[i2]) i2 = e;
    const float w0 = wgt[0], w1 = wgt[1];
#pragma unroll
    for (int e = 0; e < NEXP; ++e) {
      c0[e * TOKENS + m] = (e == i1 || e == i2) ? w0 * g[e] : 0.f;
      c1[e * TOKENS + m] = w1 * f[e];
    }
  }
}

// ---------------- fp32 -> bf16 (X) ----------------
__global__ __launch_bounds__(256)
void k_cvt(const float* __restrict__ in, bf16_t* __restrict__ out)
{
  const size_t i = ((size_t)blockIdx.x * 256 + threadIdx.x) * 8;
  const float4 a = *(const float4*)(in + i);
  const float4 b = *(const float4*)(in + i + 4);
  bf16x8 o;
  o[0] = (bf16_t)a.x; o[1] = (bf16_t)a.y; o[2] = (bf16_t)a.z; o[3] = (bf16_t)a.w;
  o[4] = (bf16_t)b.x; o[5] = (bf16_t)b.y; o[6] = (bf16_t)b.z; o[7] = (bf16_t)b.w;
  *(bf16x8*)(out + i) = o;
}

// ---------------- fp32 W[k][n] -> bf16 Wt[n][k] (64x64 tile via LDS) ----------------
#define TP 68
__global__ __launch_bounds__(256)
void k_cvt_wt(const float* __restrict__ W, bf16_t* __restrict__ Wt)
{
  __shared__ __attribute__((aligned(16))) bf16_t tile[64 * TP];
  const size_t eoff = (size_t)blockIdx.z * DDIM * DDIM;
  const float* w = W + eoff;
  bf16_t* wt = Wt + eoff;
  const int k0 = blockIdx.x * 64;
  const int n0 = blockIdx.y * 64;
  const int t = threadIdx.x;
  const int c4 = (t & 15) * 4;
  const int rb = (t >> 4) * 4;
#pragma unroll
  for (int rr = 0; rr < 4; ++rr) {
    const int r = rb + rr;
    const float4 v = *(const float4*)(w + (size_t)(k0 + r) * DDIM + n0 + c4);
    tile[(c4 + 0) * TP + r] = (bf16_t)v.x;
    tile[(c4 + 1) * TP + r] = (bf16_t)v.y;
    tile[(c4 + 2) * TP + r] = (bf16_t)v.z;
    tile[(c4 + 3) * TP + r] = (bf16_t)v.w;
  }
  __syncthreads();
  const int nl = t >> 2;
  const int kq = (t & 3) * 16;
  bf16_t* dst = wt + (size_t)(n0 + nl) * DDIM + k0 + kq;
#pragma unroll
  for (int j2 = 0; j2 < 4; ++j2) {
    bf16x4 u = *(const bf16x4*)(&tile[nl * TP + kq + j2 * 4]);
    *(bf16x4*)(dst + j2 * 4) = u;
  }
}

// =====================================================================================
// 8-phase 256x128 GEMM template (T2 st_16x32 swizzle + T3/T4 counted vmcnt + T5 setprio)
//   - K panels of 32 cols; LDS ring of 4 units per matrix (A: 16KiB, B: 8KiB units)
//   - unit(p) = p & 3; tile t reads panels 2t (phase1) and 2t+1 (phase2)
//   - tile t issues panel 2t+3 (phase1) and 2t+4 (phase2); end-of-tile vmcnt(3)
//   - swizzle: LDS byte ^= ((byte>>9)&1)<<5, applied as pre-swizzled global src +
//     swizzled ds_read addr (global_load_lds dest stays linear)
// =====================================================================================

// read a bf16x8 fragment: row R (swizzled), k-quad KQ within the 32-col panel
#define FRG(base, R, KQ) \
  (*(const bf16x8*)((base) + ((((R) * 32 + (KQ)) ^ ((((R) >> 3) & 1) << 4)))))

#define MFMA_(d, x, y) (d) = __builtin_amdgcn_mfma_f32_16x16x32_bf16((x), (y), (d), 0, 0, 0)

// one phase: 10 ds_read_b128 + 1 panel prefetch + barrier/lgkm/setprio + 16 MFMA
#define PHASE(U, PA, STA, STB, NP) do { \
    bf16x8 _a[8], _b0, _b1; \
    _Pragma("unroll") \
    for (int _i = 0; _i < 8; ++_i) _a[_i] = FRG(AsF + (U) * 8192, wm + _i * 16 + fr, kq); \
    _b0 = FRG(BsF + (U) * 4096, wn + fr, kq); \
    _b1 = FRG(BsF + (U) * 4096, wn + 16 + fr, kq); \
    if ((PA) < (NP)) { STA(PA, (PA) & 3); STB(PA, (PA) & 3); } \
    BAR(); LGKM0(); \
    __builtin_amdgcn_s_setprio(1); \
    _Pragma("unroll") \
    for (int _i = 0; _i < 8; ++_i) { MFMA_(acc[_i][0], _a[_i], _b0); MFMA_(acc[_i][1], _a[_i], _b1); } \
    __builtin_amdgcn_s_setprio(0); \
  } while (0)

#define TILE(U0, U1, PA, PB, STA, STB, NP) do { \
    PHASE(U0, PA, STA, STB, NP); \
    BAR(); \
    PHASE(U1, PB, STA, STB, NP); \
    if ((PB) < (NP)) { VMC(3); } else { VMC(0); } \
    BAR(); \
  } while (0)

// ---------------- GEMM1 (all experts): hidden_e = relu(X @ W1_e + b1_e), bf16 ----------------
// grid (16, 16, 8), 512 threads. A [4096,2048] bf16; W1t [E][n][k] bf16; hidden [E][4096][2048] bf16.
__global__ __launch_bounds__(512, 2)
void k_gemm1_8p(const bf16_t* __restrict__ A, const bf16_t* __restrict__ W1t,
                const float* __restrict__ b1, bf16_t* __restrict__ Hd)
{
  __shared__ __attribute__((aligned(16))) bf16_t AsF[4 * 8192];  // 4 x 16KiB (256x32 panels)
  __shared__ __attribute__((aligned(16))) bf16_t BsF[4 * 4096];  // 4 x  8KiB (128x32 panels)
  const int e = blockIdx.z;
  const int t = threadIdx.x;
  const int wave = t >> 6, lane = t & 63;
  const int m0 = blockIdx.x * 256, n0 = blockIdx.y * 128;
  const int wm = (wave >> 2) * 128, wn = (wave & 3) * 32;
  const int fr = lane & 15, kq = (lane >> 4) * 8;

  // staging coords: linear LDS slot (wave,lane) -> inverse-swizzled global (row,col)
  const int sRw = wave * 16 + (lane >> 2);
  const int sC  = ((lane & 3) * 8) ^ (((lane >> 5) & 1) << 4);
  const bf16_t* aSrc = A + (size_t)(m0 + sRw) * GK + sC;
  const bf16_t* bSrc = W1t + (size_t)e * GN * GK + (size_t)(n0 + sRw) * GK + sC;
  bf16_t* aDst = AsF + wave * 512;
  bf16_t* bDst = BsF + wave * 512;

#define STA1(p, u) do { const bf16_t* _s = aSrc + (size_t)(p) * 32; \
    gld_lds16(_s, aDst + (u) * 8192); \
    gld_lds16(_s + (size_t)128 * GK, aDst + (u) * 8192 + 4096); } while (0)
#define STB1(p, u) gld_lds16(bSrc + (size_t)(p) * 32, bDst + (u) * 4096)

  f32x4 acc[8][2] = {};

  // prologue: stage panels 0..2, keep panel 2 in flight
  STA1(0, 0); STB1(0, 0);
  STA1(1, 1); STB1(1, 1);
  STA1(2, 2); STB1(2, 2);
  asm volatile("s_waitcnt vmcnt(3)" ::: "memory");
  BAR();

#pragma unroll 1
  for (int tt = 0; tt < 32; tt += 2) {
    TILE(0, 1, 2 * tt + 3, 2 * tt + 4, STA1, STB1, 64);
    TILE(2, 3, 2 * tt + 5, 2 * tt + 6, STA1, STB1, 64);
  }

  // epilogue: bias + relu -> bf16
  const float* bias = b1 + (size_t)e * DDIM;
  bf16_t* Hb = Hd + (size_t)e * TOKENS * DDIM;
  const int ecol = lane & 15, erow = (lane >> 4) * 4;
#pragma unroll
  for (int j = 0; j < 2; ++j) {
    const int gn = n0 + wn + j * 16 + ecol;
    const float bv = bias[gn];
#pragma unroll
    for (int i = 0; i < 8; ++i) {
      const int gm = m0 + wm + i * 16 + erow;
#pragma unroll
      for (int r = 0; r < 4; ++r) {
        float v = acc[i][j][r] + bv;
        v = v > 0.f ? v : 0.f;
        Hb[(size_t)(gm + r) * DDIM + gn] = (bf16_t)v;
      }
    }
  }
#undef STA1
#undef STB1
}

// ---------------- GEMM2 (expert-summed): out = sum_e c_e[m] * (hidden_e @ W2_e + b2_e) ----------------
// grid (16, 16), 512 threads. All 8 experts looped in-kernel (K_total = 16384), combine-fold per expert.
__global__ __launch_bounds__(512, 2)
void k_gemm2_8p(const bf16_t* __restrict__ Hd, const bf16_t* __restrict__ W2t,
                const float* __restrict__ b2,
                const float* __restrict__ c0, const float* __restrict__ c1,
                float* __restrict__ out0, float* __restrict__ out1)
{
  __shared__ __attribute__((aligned(16))) bf16_t AsF[4 * 8192];
  __shared__ __attribute__((aligned(16))) bf16_t BsF[4 * 4096];
  __shared__ float cs[NEXP][256];    // combine coeff for this block's 256 rows, per expert
  __shared__ float bsh[NEXP][128];   // bias for this block's 128 cols, per expert

  const int t = threadIdx.x;
  const int wave = t >> 6, lane = t & 63;
  const int m0 = blockIdx.x * 256, n0 = blockIdx.y * 128;
  const int wm = (wave >> 2) * 128, wn = (wave & 3) * 32;
  const int fr = lane & 15, kq = (lane >> 4) * 8;
  const bool hi = (n0 >= HDIM);
  const float* cc = hi ? c1 : c0;

  for (int idx = t; idx < NEXP * 256; idx += 512) {
    const int ee = idx >> 8, r = idx & 255;
    cs[ee][r] = cc[ee * TOKENS + m0 + r];
  }
  for (int idx = t; idx < NEXP * 128; idx += 512) {
    const int ee = idx >> 7, r = idx & 127;
    bsh[ee][r] = b2[ee * DDIM + n0 + r];
  }

  const int sRw = wave * 16 + (lane >> 2);
  const int sC  = ((lane & 3) * 8) ^ (((lane >> 5) & 1) << 4);
  const bf16_t* aSrc = Hd + (size_t)(m0 + sRw) * GK + sC;    // + e*TOKENS*GK + k
  const bf16_t* bSrc = W2t + (size_t)(n0 + sRw) * GK + sC;   // + e*GN*GK + k
  bf16_t* aDst = AsF + wave * 512;
  bf16_t* bDst = BsF + wave * 512;

#define STA2(p, u) do { \
    const bf16_t* _s = aSrc + (size_t)((p) >> 6) * ((size_t)TOKENS * GK) + (size_t)(((p) & 63) * 32); \
    gld_lds16(_s, aDst + (u) * 8192); \
    gld_lds16(_s + (size_t)128 * GK, aDst + (u) * 8192 + 4096); } while (0)
#define STB2(p, u) do { \
    const bf16_t* _s = bSrc + (size_t)((p) >> 6) * ((size_t)GN * GK) + (size_t)(((p) & 63) * 32); \
    gld_lds16(_s, bDst + (u) * 4096); } while (0)

  f32x4 acc[8][2] = {};
  f32x4 fin[8][2] = {};

  STA2(0, 0); STB2(0, 0);
  STA2(1, 1); STB2(1, 1);
  STA2(2, 2); STB2(2, 2);
  asm volatile("s_waitcnt vmcnt(3) lgkmcnt(0)" ::: "memory");
  BAR();

  const int ecol = lane & 15, erow = (lane >> 4) * 4;

#pragma unroll 1
  for (int ex = 0; ex < NEXP; ++ex) {
#pragma unroll 1
    for (int tt = 0; tt < 32; tt += 2) {
      const int gt = ex * 32 + tt;
      TILE(0, 1, 2 * gt + 3, 2 * gt + 4, STA2, STB2, 512);
      TILE(2, 3, 2 * gt + 5, 2 * gt + 6, STA2, STB2, 512);
    }
    // fold expert ex: fin += c_ex[row] * (acc + b2_ex[col]); reset acc
#pragma unroll
    for (int j = 0; j < 2; ++j) {
      const float bv = bsh[ex][wn + j * 16 + ecol];
#pragma unroll
      for (int i = 0; i < 8; ++i) {
        const int rw = wm + i * 16 + erow;
#pragma unroll
        for (int r = 0; r < 4; ++r) {
          fin[i][j][r] += cs[ex][rw + r] * (acc[i][j][r] + bv);
          acc[i][j][r] = 0.f;
        }
      }
    }
  }

  // epilogue: write fp32 output exactly once
#pragma unroll
  for (int j = 0; j < 2; ++j) {
    const int gn = n0 + wn + j * 16 + ecol;
    float* ob = hi ? (out1 + (gn - HDIM)) : (out0 + gn);
#pragma unroll
    for (int i = 0; i < 8; ++i) {
      const int gm = m0 + wm + i * 16 + erow;
#pragma unroll
      for (int r = 0; r < 4; ++r)
        ob[(size_t)(gm + r) * HDIM] = fin[i][j][r];
    }
  }
#undef STA2
#undef STB2
}

// ---------------- legacy 128^2 kernels (small-ws fallback path) ----------------
__global__ __launch_bounds__(256, 2)
void k_gemm_relu(const bf16_t* __restrict__ A, const bf16_t* __restrict__ W1t,
                 const float* __restrict__ b1, bf16_t* __restrict__ Hd)
{
  __shared__ __attribute__((aligned(16))) bf16_t As[128 * 32];
  __shared__ __attribute__((aligned(16))) bf16_t Bs[128 * 32];
  const int e = blockIdx.z;
  const bf16_t* Bt = W1t + (size_t)e * GK * GN;
  const float* bias = b1 + (size_t)e * GN;
  bf16_t* H = Hd + (size_t)e * TOKENS * GN;

  const int t = threadIdx.x;
  const int wave = t >> 6;
  const int lane = t & 63;
  const int m0 = blockIdx.x * 128;
  const int n0 = blockIdx.y * 128;
  const int wm = (wave >> 1) << 6;
  const int wn = (wave & 1) << 6;

  f32x4 acc[4][4] = {};

  const bf16_t* aP0 = A + (size_t)(m0 + (t >> 2)) * GK + (t & 3) * 8;
  const bf16_t* aP1 = aP0 + (size_t)64 * GK;
  const bf16_t* bP0 = Bt + (size_t)(n0 + (t >> 2)) * GK + (t & 3) * 8;
  const bf16_t* bP1 = bP0 + (size_t)64 * GK;
  bf16_t* lA0 = As + wave * 512;
  bf16_t* lA1 = As + 2048 + wave * 512;
  bf16_t* lB0 = Bs + wave * 512;
  bf16_t* lB1 = Bs + 2048 + wave * 512;

  const int fr = lane & 15;
  const int kq = (lane >> 4) * 8;

  for (int k0 = 0; k0 < GK; k0 += 32) {
    gld_lds16(aP0 + k0, lA0);
    gld_lds16(aP1 + k0, lA1);
    gld_lds16(bP0 + k0, lB0);
    gld_lds16(bP1 + k0, lB1);
    __syncthreads();
    bf16x8 afr[4], bfr[4];
#pragma unroll
    for (int i = 0; i < 4; ++i) {
      afr[i] = *(const bf16x8*)(As + (wm + i * 16 + fr) * 32 + kq);
      bfr[i] = *(const bf16x8*)(Bs + (wn + i * 16 + fr) * 32 + kq);
    }
#pragma unroll
    for (int i = 0; i < 4; ++i)
#pragma unroll
      for (int j = 0; j < 4; ++j)
        acc[i][j] = __builtin_amdgcn_mfma_f32_16x16x32_bf16(afr[i], bfr[j], acc[i][j], 0, 0, 0);
    __syncthreads();
  }

  const int col = lane & 15;
  const int rq  = (lane >> 4) * 4;
#pragma unroll
  for (int j = 0; j < 4; ++j) {
    const int gn = n0 + wn + j * 16 + col;
    const float bv = bias[gn];
#pragma unroll
    for (int i = 0; i < 4; ++i) {
      const int gm = m0 + wm + i * 16 + rq;
#pragma unroll
      for (int r = 0; r < 4; ++r) {
        float v = acc[i][j][r] + bv;
        v = v > 0.f ? v : 0.f;
        H[(size_t)(gm + r) * GN + gn] = (bf16_t)v;
      }
    }
  }
}

__global__ __launch_bounds__(256, 2)
void k_gemm_out(const bf16_t* __restrict__ A, const bf16_t* __restrict__ Bt,
                const float* __restrict__ bias,
                const float* __restrict__ c0, const float* __restrict__ c1,
                float* __restrict__ out0, float* __restrict__ out1, const int accum)
{
  __shared__ __attribute__((aligned(16))) bf16_t As[128 * 32];
  __shared__ __attribute__((aligned(16))) bf16_t Bs[128 * 32];
  const int t = threadIdx.x;
  const int wave = t >> 6;
  const int lane = t & 63;
  const int m0 = blockIdx.x * 128;
  const int n0 = blockIdx.y * 128;
  const int wm = (wave >> 1) << 6;
  const int wn = (wave & 1) << 6;

  f32x4 acc[4][4] = {};

  const bf16_t* aP0 = A + (size_t)(m0 + (t >> 2)) * GK + (t & 3) * 8;
  const bf16_t* aP1 = aP0 + (size_t)64 * GK;
  const bf16_t* bP0 = Bt + (size_t)(n0 + (t >> 2)) * GK + (t & 3) * 8;
  const bf16_t* bP1 = bP0 + (size_t)64 * GK;
  bf16_t* lA0 = As + wave * 512;
  bf16_t* lA1 = As + 2048 + wave * 512;
  bf16_t* lB0 = Bs + wave * 512;
  bf16_t* lB1 = Bs + 2048 + wave * 512;

  const int fr = lane & 15;
  const int kq = (lane >> 4) * 8;

  for (int k0 = 0; k0 < GK; k0 += 32) {
    gld_lds16(aP0 + k0, lA0);
    gld_lds16(aP1 + k0, lA1);
    gld_lds16(bP0 + k0, lB0);
    gld_lds16(bP1 + k0, lB1);
    __syncthreads();
    bf16x8 afr[4], bfr[4];
#pragma unroll
    for (int i = 0; i < 4; ++i) {
      afr[i] = *(const bf16x8*)(As + (wm + i * 16 + fr) * 32 + kq);
      bfr[i] = *(const bf16x8*)(Bs + (wn + i * 16 + fr) * 32 + kq);
    }
#pragma unroll
    for (int i = 0; i < 4; ++i)
#pragma unroll
      for (int j = 0; j < 4; ++j)
        acc[i][j] = __builtin_amdgcn_mfma_f32_16x16x32_bf16(afr[i], bfr[j], acc[i][j], 0, 0, 0);
    __syncthreads();
  }

  const int col = lane & 15;
  const int rq  = (lane >> 4) * 4;
#pragma unroll
  for (int j = 0; j < 4; ++j) {
    const int gn = n0 + wn + j * 16 + col;
    const float bv = bias[gn];
    const bool lo = gn < HDIM;
    float* obase = lo ? (out0 + gn) : (out1 + (gn - HDIM));
    const float* cc = lo ? c0 : c1;
#pragma unroll
    for (int i = 0; i < 4; ++i) {
      const int gmB = m0 + wm + i * 16 + rq;
#pragma unroll
      for (int r = 0; r < 4; ++r) {
        const int gm = gmB + r;
        float v = (acc[i][j][r] + bv) * cc[gm];
        float* dst = obase + (size_t)gm * HDIM;
        if (accum) v += *dst;
        *dst = v;
      }
    }
  }
}

extern "C" void kernel_launch(void* const* d_in, const int* in_sizes, int n_in,
                              void* d_out, int out_size, void* d_ws, size_t ws_size,
                              hipStream_t stream)
{
  const float* vec = (const float*)d_in[0];
  const float* Wg  = (const float*)d_in[1];
  const float* bg  = (const float*)d_in[2];
  const float* Wf  = (const float*)d_in[3];
  const float* bfv = (const float*)d_in[4];
  const float* W1  = (const float*)d_in[5];
  const float* b1  = (const float*)d_in[6];
  const float* W2  = (const float*)d_in[7];
  const float* b2  = (const float*)d_in[8];
  const float* wgt = (const float*)d_in[9];

  float* out0 = (float*)d_out;
  float* out1 = out0 + (size_t)TOKENS * HDIM;

  char* base = (char*)d_ws;
  const size_t XB = (size_t)TOKENS * DDIM * 2;        // 16 MiB
  const size_t HB = (size_t)NEXP * TOKENS * DDIM * 2; // 128 MiB
  const size_t WT = (size_t)NEXP * DDIM * DDIM * 2;   // 64 MiB each

  bf16_t* Xbf = (bf16_t*)base;
  float*  c0  = (float*)(base + XB);
  float*  c1  = c0 + (size_t)NEXP * TOKENS;
  size_t off = XB + 2 * (size_t)NEXP * TOKENS * 4;

  k_routing<<<dim3(TOKENS / 4), 256, 0, stream>>>(vec, Wg, bg, Wf, bfv, wgt, c0, c1);
  k_cvt<<<dim3((TOKENS * DDIM) / 2048), 256, 0, stream>>>(vec, Xbf);

  if (ws_size >= off + HB + 2 * WT) {
    // big path: per-expert hidden + both weight tensors pre-converted, 8-phase GEMMs
    bf16_t* hidden = (bf16_t*)(base + off);
    bf16_t* W1t    = (bf16_t*)(base + off + HB);
    bf16_t* W2t    = (bf16_t*)(base + off + HB + WT);
    k_cvt_wt<<<dim3(32, 32, NEXP), 256, 0, stream>>>(W1, W1t);
    k_cvt_wt<<<dim3(32, 32, NEXP), 256, 0, stream>>>(W2, W2t);
    k_gemm1_8p<<<dim3(16, 16, NEXP), 512, 0, stream>>>(Xbf, W1t, b1, hidden);
    k_gemm2_8p<<<dim3(16, 16), 512, 0, stream>>>(hidden, W2t, b2, c0, c1, out0, out1);
  } else {
    // small-ws fallback: sequential per-expert with reused buffers (legacy kernels)
    bf16_t* hidden = (bf16_t*)(base + off);
    bf16_t* W1t    = hidden + (size_t)TOKENS * DDIM;
    bf16_t* W2t    = W1t + (size_t)DDIM * DDIM;
    for (int e = 0; e < NEXP; ++e) {
      k_cvt_wt<<<dim3(32, 32, 1), 256, 0, stream>>>(W1 + (size_t)e * DDIM * DDIM, W1t);
      k_cvt_wt<<<dim3(32, 32, 1), 256, 0, stream>>>(W2 + (size_t)e * DDIM * DDIM, W2t);
      k_gemm_relu<<<dim3(32, 16, 1), 256, 0, stream>>>(Xbf, W1t, b1 + (size_t)e * DDIM, hidden);
      k_gemm_out<<<dim3(32, 16), 256, 0, stream>>>(
          hidden, W2t, b2 + (size_t)e * DDIM,
          c0 + (size_t)e * TOKENS, c1 + (size_t)e * TOKENS, out0, out1, e > 0);
    }
  }
}

// Round 2
// 956.508 us; speedup vs baseline: 1.1205x; 1.0968x over previous
//
#include <hip/hip_runtime.h>

#define TOKENS 4096
#define DDIM   2048
#define HDIM   1024
#define NEXP   8
#define GK     2048
#define GN     2048

typedef __bf16 bf16_t;
typedef __bf16 bf16x8 __attribute__((ext_vector_type(8)));
typedef __bf16 bf16x4 __attribute__((ext_vector_type(4)));
typedef float  f32x4  __attribute__((ext_vector_type(4)));

__device__ inline void gld_lds16(const bf16_t* g, bf16_t* l) {
  __builtin_amdgcn_global_load_lds(
      (const __attribute__((address_space(1))) void*)g,
      (__attribute__((address_space(3))) void*)l, 16, 0, 0);
}

#define LGKM0() asm volatile("s_waitcnt lgkmcnt(0)" ::: "memory")
#define VMC(n)  asm volatile("s_waitcnt vmcnt(" #n ")" ::: "memory")
#define BAR()   __builtin_amdgcn_s_barrier()

// ---------------- routing: gate_g (softmax+top2) and gate_f (softmax), fold weight[] ----------------
__global__ __launch_bounds__(256)
void k_routing(const float* __restrict__ vec,
               const float* __restrict__ Wg, const float* __restrict__ bg,
               const float* __restrict__ Wf, const float* __restrict__ bfv,
               const float* __restrict__ wgt,
               float* __restrict__ c0, float* __restrict__ c1)
{
  const int wave = threadIdx.x >> 6;
  const int lane = threadIdx.x & 63;
  const int m = blockIdx.x * 4 + wave;
  const float* v = vec + (size_t)m * DDIM;

  float ag[NEXP], af[NEXP];
#pragma unroll
  for (int e = 0; e < NEXP; ++e) { ag[e] = 0.f; af[e] = 0.f; }

  for (int i = lane; i < HDIM; i += 64) {
    const float xg = v[i];
    const float xf = v[HDIM + i];
    const float4 wg0 = *(const float4*)(Wg + i * NEXP);
    const float4 wg1 = *(const float4*)(Wg + i * NEXP + 4);
    const float4 wf0 = *(const float4*)(Wf + i * NEXP);
    const float4 wf1 = *(const float4*)(Wf + i * NEXP + 4);
    ag[0] += xg * wg0.x; ag[1] += xg * wg0.y; ag[2] += xg * wg0.z; ag[3] += xg * wg0.w;
    ag[4] += xg * wg1.x; ag[5] += xg * wg1.y; ag[6] += xg * wg1.z; ag[7] += xg * wg1.w;
    af[0] += xf * wf0.x; af[1] += xf * wf0.y; af[2] += xf * wf0.z; af[3] += xf * wf0.w;
    af[4] += xf * wf1.x; af[5] += xf * wf1.y; af[6] += xf * wf1.z; af[7] += xf * wf1.w;
  }
#pragma unroll
  for (int e = 0; e < NEXP; ++e) {
#pragma unroll
    for (int off = 32; off >= 1; off >>= 1) {
      ag[e] += __shfl_xor(ag[e], off, 64);
      af[e] += __shfl_xor(af[e], off, 64);
    }
  }
  if (lane == 0) {
    float g[NEXP], f[NEXP];
    float mg = -1e30f, mf = -1e30f;
#pragma unroll
    for (int e = 0; e < NEXP; ++e) {
      g[e] = ag[e] + bg[e]; mg = fmaxf(mg, g[e]);
      f[e] = af[e] + bfv[e]; mf = fmaxf(mf, f[e]);
    }
    float sg = 0.f, sf = 0.f;
#pragma unroll
    for (int e = 0; e < NEXP; ++e) {
      g[e] = expf(g[e] - mg); sg += g[e];
      f[e] = expf(f[e] - mf); sf += f[e];
    }
    const float rg = 1.f / sg, rf = 1.f / sf;
#pragma unroll
    for (int e = 0; e < NEXP; ++e) { g[e] *= rg; f[e] *= rf; }
    int i1 = 0;
#pragma unroll
    for (int e = 1; e < NEXP; ++e) if (g[e] > g[i1]) i1 = e;
    int i2 = (i1 == 0) ? 1 : 0;
#pragma unroll
    for (int e = 0; e < NEXP; ++e) if (e != i1 && g[e] > g[i2]) i2 = e;
    const float w0 = wgt[0], w1 = wgt[1];
#pragma unroll
    for (int e = 0; e < NEXP; ++e) {
      c0[e * TOKENS + m] = (e == i1 || e == i2) ? w0 * g[e] : 0.f;
      c1[e * TOKENS + m] = w1 * f[e];
    }
  }
}

// ---------------- fp32 -> bf16 (X) ----------------
__global__ __launch_bounds__(256)
void k_cvt(const float* __restrict__ in, bf16_t* __restrict__ out)
{
  const size_t i = ((size_t)blockIdx.x * 256 + threadIdx.x) * 8;
  const float4 a = *(const float4*)(in + i);
  const float4 b = *(const float4*)(in + i + 4);
  bf16x8 o;
  o[0] = (bf16_t)a.x; o[1] = (bf16_t)a.y; o[2] = (bf16_t)a.z; o[3] = (bf16_t)a.w;
  o[4] = (bf16_t)b.x; o[5] = (bf16_t)b.y; o[6] = (bf16_t)b.z; o[7] = (bf16_t)b.w;
  *(bf16x8*)(out + i) = o;
}

// ---------------- fp32 W[k][n] -> bf16 Wt[n][k] (64x64 tile via LDS) ----------------
#define TP 68
__global__ __launch_bounds__(256)
void k_cvt_wt(const float* __restrict__ W, bf16_t* __restrict__ Wt)
{
  __shared__ __attribute__((aligned(16))) bf16_t tile[64 * TP];
  const size_t eoff = (size_t)blockIdx.z * DDIM * DDIM;
  const float* w = W + eoff;
  bf16_t* wt = Wt + eoff;
  const int k0 = blockIdx.x * 64;
  const int n0 = blockIdx.y * 64;
  const int t = threadIdx.x;
  const int c4 = (t & 15) * 4;
  const int rb = (t >> 4) * 4;
#pragma unroll
  for (int rr = 0; rr < 4; ++rr) {
    const int r = rb + rr;
    const float4 v = *(const float4*)(w + (size_t)(k0 + r) * DDIM + n0 + c4);
    tile[(c4 + 0) * TP + r] = (bf16_t)v.x;
    tile[(c4 + 1) * TP + r] = (bf16_t)v.y;
    tile[(c4 + 2) * TP + r] = (bf16_t)v.z;
    tile[(c4 + 3) * TP + r] = (bf16_t)v.w;
  }
  __syncthreads();
  const int nl = t >> 2;
  const int kq = (t & 3) * 16;
  bf16_t* dst = wt + (size_t)(n0 + nl) * DDIM + k0 + kq;
#pragma unroll
  for (int j2 = 0; j2 < 4; ++j2) {
    bf16x4 u = *(const bf16x4*)(&tile[nl * TP + kq + j2 * 4]);
    *(bf16x4*)(dst + j2 * 4) = u;
  }
}

// =====================================================================================
// Per-panel pipelined GEMM (T2 swizzle + T4 counted vmcnt + T5 setprio).
//   K panels of 32 cols; ring of 4 LDS units per matrix; 3 panels in flight.
//   Phase p: {ds_read frags(unit p&3) | stage panel p+3 | lgkm0 | MFMA | vmcnt(F) | bar}
//   Every phase does lgkm0 before its barrier -> staging into unit (p-1)&3 is WAR-safe.
// =====================================================================================

// read a bf16x8 fragment: row R (swizzled), k-quad KQ within the 32-col panel
#define FRG(base, R, KQ) \
  (*(const bf16x8*)((base) + ((((R) * 32 + (KQ)) ^ ((((R) >> 3) & 1) << 4)))))

#define MFMA_(d, x, y) (d) = __builtin_amdgcn_mfma_f32_16x16x32_bf16((x), (y), (d), 0, 0, 0)

// ---------------- GEMM1 (all experts): hidden_e = relu(X @ W1_e + b1_e), bf16 ----------------
// 256x256 block, 8 waves (2Mx4N), wave tile 128x64. grid (16, 8, 8), 512 threads.
// LDS: A ring 4x16KiB + B ring 4x16KiB = 128 KiB. 4 gld_lds16 per panel -> vmcnt(8) steady.
__global__ __launch_bounds__(512, 2)
void k_gemm1_8p(const bf16_t* __restrict__ A, const bf16_t* __restrict__ W1t,
                const float* __restrict__ b1, bf16_t* __restrict__ Hd)
{
  __shared__ __attribute__((aligned(16))) bf16_t AsF[4 * 8192];
  __shared__ __attribute__((aligned(16))) bf16_t BsF[4 * 8192];
  const int e = blockIdx.z;
  const int t = threadIdx.x;
  const int wave = t >> 6, lane = t & 63;
  const int m0 = blockIdx.x * 256, n0 = blockIdx.y * 256;
  const int wm = (wave >> 2) * 128, wn = (wave & 3) * 64;
  const int fr = lane & 15, kq = (lane >> 4) * 8;

  // staging coords: linear LDS slot (wave,lane) -> inverse-swizzled global (row,col)
  const int sRw = wave * 16 + (lane >> 2);
  const int sC  = ((lane & 3) * 8) ^ (((lane >> 5) & 1) << 4);
  const bf16_t* aSrc = A + (size_t)(m0 + sRw) * GK + sC;
  const bf16_t* bSrc = W1t + (size_t)e * GN * GK + (size_t)(n0 + sRw) * GK + sC;
  bf16_t* aDst = AsF + wave * 512;
  bf16_t* bDst = BsF + wave * 512;

#define STA1(P, U) do { const bf16_t* _s = aSrc + (size_t)(P) * 32; \
    gld_lds16(_s, aDst + (U) * 8192); \
    gld_lds16(_s + (size_t)128 * GK, aDst + (U) * 8192 + 4096); } while (0)
#define STB1(P, U) do { const bf16_t* _s = bSrc + (size_t)(P) * 32; \
    gld_lds16(_s, bDst + (U) * 8192); \
    gld_lds16(_s + (size_t)128 * GK, bDst + (U) * 8192 + 4096); } while (0)

  f32x4 acc[8][4] = {};

#define PH1(U, SP, SU, DOST) do { \
    bf16x8 a_[8], b_[4]; \
    _Pragma("unroll") \
    for (int _i = 0; _i < 8; ++_i) a_[_i] = FRG(AsF + (U) * 8192, wm + _i * 16 + fr, kq); \
    _Pragma("unroll") \
    for (int _j = 0; _j < 4; ++_j) b_[_j] = FRG(BsF + (U) * 8192, wn + _j * 16 + fr, kq); \
    if (DOST) { STA1(SP, SU); STB1(SP, SU); } \
    LGKM0(); \
    __builtin_amdgcn_s_setprio(1); \
    _Pragma("unroll") \
    for (int _i = 0; _i < 8; ++_i) \
      _Pragma("unroll") \
      for (int _j = 0; _j < 4; ++_j) MFMA_(acc[_i][_j], a_[_i], b_[_j]); \
    __builtin_amdgcn_s_setprio(0); \
  } while (0)

  // prologue: panels 0..2 in flight (12 loads), drain panel 0
  STA1(0, 0); STB1(0, 0);
  STA1(1, 1); STB1(1, 1);
  STA1(2, 2); STB1(2, 2);
  VMC(8); BAR();

#pragma unroll 1
  for (int pb = 0; pb < 60; pb += 4) {
    PH1(0, pb + 3, 3, 1); VMC(8); BAR();
    PH1(1, pb + 4, 0, 1); VMC(8); BAR();
    PH1(2, pb + 5, 1, 1); VMC(8); BAR();
    PH1(3, pb + 6, 2, 1); VMC(8); BAR();
  }
  PH1(0, 63, 3, 1); VMC(8); BAR();
  PH1(1, 0, 0, 0);  VMC(4); BAR();
  PH1(2, 0, 0, 0);  VMC(0); BAR();
  PH1(3, 0, 0, 0);

  // epilogue: bias + relu -> bf16
  const float* bias = b1 + (size_t)e * DDIM;
  bf16_t* Hb = Hd + (size_t)e * TOKENS * DDIM;
  const int ecol = lane & 15, erow = (lane >> 4) * 4;
#pragma unroll
  for (int j = 0; j < 4; ++j) {
    const int gn = n0 + wn + j * 16 + ecol;
    const float bv = bias[gn];
#pragma unroll
    for (int i = 0; i < 8; ++i) {
      const int gm = m0 + wm + i * 16 + erow;
#pragma unroll
      for (int r = 0; r < 4; ++r) {
        float v = acc[i][j][r] + bv;
        v = v > 0.f ? v : 0.f;
        Hb[(size_t)(gm + r) * DDIM + gn] = (bf16_t)v;
      }
    }
  }
#undef PH1
#undef STA1
#undef STB1
}

// ---------------- GEMM2 (expert-summed): out = sum_e c_e[m] * (hidden_e @ W2_e + b2_e) ----------------
// 128x256 block, 8 waves (2Mx4N), wave tile 64x64. grid (32, 8), 512 threads (256 blocks = 1/CU).
// LDS: A ring 4x8KiB + B ring 4x16KiB = 96 KiB (+cs/bsh). 3 gld_lds16 per panel -> vmcnt(6) steady.
// 512 K-panels total (8 experts x 64); per-expert combine-fold at expert boundary.
__global__ __launch_bounds__(512, 2)
void k_gemm2_8p(const bf16_t* __restrict__ Hd, const bf16_t* __restrict__ W2t,
                const float* __restrict__ b2,
                const float* __restrict__ c0, const float* __restrict__ c1,
                float* __restrict__ out0, float* __restrict__ out1)
{
  __shared__ __attribute__((aligned(16))) bf16_t AsF[4 * 4096];
  __shared__ __attribute__((aligned(16))) bf16_t BsF[4 * 8192];
  __shared__ float cs[NEXP][128];    // combine coeff for this block's 128 rows, per expert
  __shared__ float bsh[NEXP][256];   // bias for this block's 256 cols, per expert

  const int t = threadIdx.x;
  const int wave = t >> 6, lane = t & 63;
  const int m0 = blockIdx.x * 128, n0 = blockIdx.y * 256;
  const int wm = (wave >> 2) * 64, wn = (wave & 3) * 64;
  const int fr = lane & 15, kq = (lane >> 4) * 8;
  const bool hi = (n0 >= HDIM);
  const float* cc = hi ? c1 : c0;

  for (int idx = t; idx < NEXP * 128; idx += 512) {
    const int ee = idx >> 7, r = idx & 127;
    cs[ee][r] = cc[ee * TOKENS + m0 + r];
  }
  for (int idx = t; idx < NEXP * 256; idx += 512) {
    const int ee = idx >> 8, r = idx & 255;
    bsh[ee][r] = b2[ee * DDIM + n0 + r];
  }
  __syncthreads();   // cs/bsh visible before first use; no staging in flight yet

  const int sRw = wave * 16 + (lane >> 2);
  const int sC  = ((lane & 3) * 8) ^ (((lane >> 5) & 1) << 4);
  const bf16_t* aSrc = Hd + (size_t)(m0 + sRw) * GK + sC;    // + e*TOKENS*GK + k
  const bf16_t* bSrc = W2t + (size_t)(n0 + sRw) * GK + sC;   // + e*GN*GK + k
  bf16_t* aDst = AsF + wave * 512;
  bf16_t* bDst = BsF + wave * 512;

#define STA2(P, U) do { \
    const bf16_t* _s = aSrc + (size_t)((P) >> 6) * ((size_t)TOKENS * GK) + (size_t)((P) & 63) * 32; \
    gld_lds16(_s, aDst + (U) * 4096); } while (0)
#define STB2(P, U) do { \
    const bf16_t* _s = bSrc + (size_t)((P) >> 6) * ((size_t)GN * GK) + (size_t)((P) & 63) * 32; \
    gld_lds16(_s, bDst + (U) * 8192); \
    gld_lds16(_s + (size_t)128 * GK, bDst + (U) * 8192 + 4096); } while (0)

  f32x4 acc[4][4] = {};
  f32x4 fin[4][4] = {};

#define PH2(U, SP, SU, DOST) do { \
    bf16x8 a_[4], b_[4]; \
    _Pragma("unroll") \
    for (int _i = 0; _i < 4; ++_i) a_[_i] = FRG(AsF + (U) * 4096, wm + _i * 16 + fr, kq); \
    _Pragma("unroll") \
    for (int _j = 0; _j < 4; ++_j) b_[_j] = FRG(BsF + (U) * 8192, wn + _j * 16 + fr, kq); \
    if (DOST) { STA2(SP, SU); STB2(SP, SU); } \
    LGKM0(); \
    __builtin_amdgcn_s_setprio(1); \
    _Pragma("unroll") \
    for (int _i = 0; _i < 4; ++_i) \
      _Pragma("unroll") \
      for (int _j = 0; _j < 4; ++_j) MFMA_(acc[_i][_j], a_[_i], b_[_j]); \
    __builtin_amdgcn_s_setprio(0); \
  } while (0)

  const int ecol = lane & 15, erow = (lane >> 4) * 4;

#define FOLD2(E) do { \
    _Pragma("unroll") \
    for (int _j = 0; _j < 4; ++_j) { \
      const float _bv = bsh[E][wn + _j * 16 + ecol]; \
      _Pragma("unroll") \
      for (int _i = 0; _i < 4; ++_i) { \
        const int _rw = wm + _i * 16 + erow; \
        _Pragma("unroll") \
        for (int _r = 0; _r < 4; ++_r) { \
          fin[_i][_j][_r] += cs[E][_rw + _r] * (acc[_i][_j][_r] + _bv); \
          acc[_i][_j][_r] = 0.f; \
        } \
      } \
    } \
  } while (0)

  // prologue: panels 0..2 in flight (9 loads), drain panel 0
  STA2(0, 0); STB2(0, 0);
  STA2(1, 1); STB2(1, 1);
  STA2(2, 2); STB2(2, 2);
  VMC(6); BAR();

#pragma unroll 1
  for (int pb = 0; pb < 508; pb += 4) {
    PH2(0, pb + 3, 3, 1); VMC(6); BAR();
    PH2(1, pb + 4, 0, 1); VMC(6); BAR();
    PH2(2, pb + 5, 1, 1); VMC(6); BAR();
    PH2(3, pb + 6, 2, 1);
    if ((pb & 63) == 60) FOLD2((pb + 3) >> 6);   // experts 0..6: after phase 64e+63
    VMC(6); BAR();
  }
  PH2(0, 511, 3, 1); VMC(6); BAR();   // phase 508, stages last panel
  PH2(1, 0, 0, 0);  VMC(3); BAR();    // phase 509
  PH2(2, 0, 0, 0);  VMC(0); BAR();    // phase 510
  PH2(3, 0, 0, 0);                    // phase 511
  FOLD2(7);

  // epilogue: write fp32 output exactly once
#pragma unroll
  for (int j = 0; j < 4; ++j) {
    const int gn = n0 + wn + j * 16 + ecol;
    float* ob = hi ? (out1 + (gn - HDIM)) : (out0 + gn);
#pragma unroll
    for (int i = 0; i < 4; ++i) {
      const int gm = m0 + wm + i * 16 + erow;
#pragma unroll
      for (int r = 0; r < 4; ++r)
        ob[(size_t)(gm + r) * HDIM] = fin[i][j][r];
    }
  }
#undef PH2
#undef STA2
#undef STB2
#undef FOLD2
}

// ---------------- legacy 128^2 kernels (small-ws fallback path) ----------------
__global__ __launch_bounds__(256, 2)
void k_gemm_relu(const bf16_t* __restrict__ A, const bf16_t* __restrict__ W1t,
                 const float* __restrict__ b1, bf16_t* __restrict__ Hd)
{
  __shared__ __attribute__((aligned(16))) bf16_t As[128 * 32];
  __shared__ __attribute__((aligned(16))) bf16_t Bs[128 * 32];
  const int e = blockIdx.z;
  const bf16_t* Bt = W1t + (size_t)e * GK * GN;
  const float* bias = b1 + (size_t)e * GN;
  bf16_t* H = Hd + (size_t)e * TOKENS * GN;

  const int t = threadIdx.x;
  const int wave = t >> 6;
  const int lane = t & 63;
  const int m0 = blockIdx.x * 128;
  const int n0 = blockIdx.y * 128;
  const int wm = (wave >> 1) << 6;
  const int wn = (wave & 1) << 6;

  f32x4 acc[4][4] = {};

  const bf16_t* aP0 = A + (size_t)(m0 + (t >> 2)) * GK + (t & 3) * 8;
  const bf16_t* aP1 = aP0 + (size_t)64 * GK;
  const bf16_t* bP0 = Bt + (size_t)(n0 + (t >> 2)) * GK + (t & 3) * 8;
  const bf16_t* bP1 = bP0 + (size_t)64 * GK;
  bf16_t* lA0 = As + wave * 512;
  bf16_t* lA1 = As + 2048 + wave * 512;
  bf16_t* lB0 = Bs + wave * 512;
  bf16_t* lB1 = Bs + 2048 + wave * 512;

  const int fr = lane & 15;
  const int kq = (lane >> 4) * 8;

  for (int k0 = 0; k0 < GK; k0 += 32) {
    gld_lds16(aP0 + k0, lA0);
    gld_lds16(aP1 + k0, lA1);
    gld_lds16(bP0 + k0, lB0);
    gld_lds16(bP1 + k0, lB1);
    __syncthreads();
    bf16x8 afr[4], bfr[4];
#pragma unroll
    for (int i = 0; i < 4; ++i) {
      afr[i] = *(const bf16x8*)(As + (wm + i * 16 + fr) * 32 + kq);
      bfr[i] = *(const bf16x8*)(Bs + (wn + i * 16 + fr) * 32 + kq);
    }
#pragma unroll
    for (int i = 0; i < 4; ++i)
#pragma unroll
      for (int j = 0; j < 4; ++j)
        acc[i][j] = __builtin_amdgcn_mfma_f32_16x16x32_bf16(afr[i], bfr[j], acc[i][j], 0, 0, 0);
    __syncthreads();
  }

  const int col = lane & 15;
  const int rq  = (lane >> 4) * 4;
#pragma unroll
  for (int j = 0; j < 4; ++j) {
    const int gn = n0 + wn + j * 16 + col;
    const float bv = bias[gn];
#pragma unroll
    for (int i = 0; i < 4; ++i) {
      const int gm = m0 + wm + i * 16 + rq;
#pragma unroll
      for (int r = 0; r < 4; ++r) {
        float v = acc[i][j][r] + bv;
        v = v > 0.f ? v : 0.f;
        H[(size_t)(gm + r) * GN + gn] = (bf16_t)v;
      }
    }
  }
}

__global__ __launch_bounds__(256, 2)
void k_gemm_out(const bf16_t* __restrict__ A, const bf16_t* __restrict__ Bt,
                const float* __restrict__ bias,
                const float* __restrict__ c0, const float* __restrict__ c1,
                float* __restrict__ out0, float* __restrict__ out1, const int accum)
{
  __shared__ __attribute__((aligned(16))) bf16_t As[128 * 32];
  __shared__ __attribute__((aligned(16))) bf16_t Bs[128 * 32];
  const int t = threadIdx.x;
  const int wave = t >> 6;
  const int lane = t & 63;
  const int m0 = blockIdx.x * 128;
  const int n0 = blockIdx.y * 128;
  const int wm = (wave >> 1) << 6;
  const int wn = (wave & 1) << 6;

  f32x4 acc[4][4] = {};

  const bf16_t* aP0 = A + (size_t)(m0 + (t >> 2)) * GK + (t & 3) * 8;
  const bf16_t* aP1 = aP0 + (size_t)64 * GK;
  const bf16_t* bP0 = Bt + (size_t)(n0 + (t >> 2)) * GK + (t & 3) * 8;
  const bf16_t* bP1 = bP0 + (size_t)64 * GK;
  bf16_t* lA0 = As + wave * 512;
  bf16_t* lA1 = As + 2048 + wave * 512;
  bf16_t* lB0 = Bs + wave * 512;
  bf16_t* lB1 = Bs + 2048 + wave * 512;

  const int fr = lane & 15;
  const int kq = (lane >> 4) * 8;

  for (int k0 = 0; k0 < GK; k0 += 32) {
    gld_lds16(aP0 + k0, lA0);
    gld_lds16(aP1 + k0, lA1);
    gld_lds16(bP0 + k0, lB0);
    gld_lds16(bP1 + k0, lB1);
    __syncthreads();
    bf16x8 afr[4], bfr[4];
#pragma unroll
    for (int i = 0; i < 4; ++i) {
      afr[i] = *(const bf16x8*)(As + (wm + i * 16 + fr) * 32 + kq);
      bfr[i] = *(const bf16x8*)(Bs + (wn + i * 16 + fr) * 32 + kq);
    }
#pragma unroll
    for (int i = 0; i < 4; ++i)
#pragma unroll
      for (int j = 0; j < 4; ++j)
        acc[i][j] = __builtin_amdgcn_mfma_f32_16x16x32_bf16(afr[i], bfr[j], acc[i][j], 0, 0, 0);
    __syncthreads();
  }

  const int col = lane & 15;
  const int rq  = (lane >> 4) * 4;
#pragma unroll
  for (int j = 0; j < 4; ++j) {
    const int gn = n0 + wn + j * 16 + col;
    const float bv = bias[gn];
    const bool lo = gn < HDIM;
    float* obase = lo ? (out0 + gn) : (out1 + (gn - HDIM));
    const float* cc = lo ? c0 : c1;
#pragma unroll
    for (int i = 0; i < 4; ++i) {
      const int gmB = m0 + wm + i * 16 + rq;
#pragma unroll
      for (int r = 0; r < 4; ++r) {
        const int gm = gmB + r;
        float v = (acc[i][j][r] + bv) * cc[gm];
        float* dst = obase + (size_t)gm * HDIM;
        if (accum) v += *dst;
        *dst = v;
      }
    }
  }
}

extern "C" void kernel_launch(void* const* d_in, const int* in_sizes, int n_in,
                              void* d_out, int out_size, void* d_ws, size_t ws_size,
                              hipStream_t stream)
{
  const float* vec = (const float*)d_in[0];
  const float* Wg  = (const float*)d_in[1];
  const float* bg  = (const float*)d_in[2];
  const float* Wf  = (const float*)d_in[3];
  const float* bfv = (const float*)d_in[4];
  const float* W1  = (const float*)d_in[5];
  const float* b1  = (const float*)d_in[6];
  const float* W2  = (const float*)d_in[7];
  const float* b2  = (const float*)d_in[8];
  const float* wgt = (const float*)d_in[9];

  float* out0 = (float*)d_out;
  float* out1 = out0 + (size_t)TOKENS * HDIM;

  char* base = (char*)d_ws;
  const size_t XB = (size_t)TOKENS * DDIM * 2;        // 16 MiB
  const size_t HB = (size_t)NEXP * TOKENS * DDIM * 2; // 128 MiB
  const size_t WT = (size_t)NEXP * DDIM * DDIM * 2;   // 64 MiB each

  bf16_t* Xbf = (bf16_t*)base;
  float*  c0  = (float*)(base + XB);
  float*  c1  = c0 + (size_t)NEXP * TOKENS;
  size_t off = XB + 2 * (size_t)NEXP * TOKENS * 4;

  k_routing<<<dim3(TOKENS / 4), 256, 0, stream>>>(vec, Wg, bg, Wf, bfv, wgt, c0, c1);
  k_cvt<<<dim3((TOKENS * DDIM) / 2048), 256, 0, stream>>>(vec, Xbf);

  if (ws_size >= off + HB + 2 * WT) {
    // big path: per-expert hidden + both weight tensors pre-converted, pipelined GEMMs
    bf16_t* hidden = (bf16_t*)(base + off);
    bf16_t* W1t    = (bf16_t*)(base + off + HB);
    bf16_t* W2t    = (bf16_t*)(base + off + HB + WT);
    k_cvt_wt<<<dim3(32, 32, NEXP), 256, 0, stream>>>(W1, W1t);
    k_cvt_wt<<<dim3(32, 32, NEXP), 256, 0, stream>>>(W2, W2t);
    k_gemm1_8p<<<dim3(16, 8, NEXP), 512, 0, stream>>>(Xbf, W1t, b1, hidden);
    k_gemm2_8p<<<dim3(32, 8), 512, 0, stream>>>(hidden, W2t, b2, c0, c1, out0, out1);
  } else {
    // small-ws fallback: sequential per-expert with reused buffers (legacy kernels)
    bf16_t* hidden = (bf16_t*)(base + off);
    bf16_t* W1t    = hidden + (size_t)TOKENS * DDIM;
    bf16_t* W2t    = W1t + (size_t)DDIM * DDIM;
    for (int e = 0; e < NEXP; ++e) {
      k_cvt_wt<<<dim3(32, 32, 1), 256, 0, stream>>>(W1 + (size_t)e * DDIM * DDIM, W1t);
      k_cvt_wt<<<dim3(32, 32, 1), 256, 0, stream>>>(W2 + (size_t)e * DDIM * DDIM, W2t);
      k_gemm_relu<<<dim3(32, 16, 1), 256, 0, stream>>>(Xbf, W1t, b1 + (size_t)e * DDIM, hidden);
      k_gemm_out<<<dim3(32, 16), 256, 0, stream>>>(
          hidden, W2t, b2 + (size_t)e * DDIM,
          c0 + (size_t)e * TOKENS, c1 + (size_t)e * TOKENS, out0, out1, e > 0);
    }
  }
}

// Round 3
// 950.985 us; speedup vs baseline: 1.1270x; 1.0058x over previous
//
#include <hip/hip_runtime.h>

#define TOKENS 4096
#define DDIM   2048
#define HDIM   1024
#define NEXP   8
#define GK     2048
#define GN     2048

typedef __bf16 bf16_t;
typedef __bf16 bf16x8 __attribute__((ext_vector_type(8)));
typedef __bf16 bf16x4 __attribute__((ext_vector_type(4)));
typedef float  f32x4  __attribute__((ext_vector_type(4)));

__device__ inline void gld_lds16(const bf16_t* g, bf16_t* l) {
  __builtin_amdgcn_global_load_lds(
      (const __attribute__((address_space(1))) void*)g,
      (__attribute__((address_space(3))) void*)l, 16, 0, 0);
}

#define VMC(n)  asm volatile("s_waitcnt vmcnt(" #n ")" ::: "memory")
#define BAR()   __builtin_amdgcn_s_barrier()

// ---------------- routing: gate_g (softmax+top2) and gate_f (softmax), fold weight[] ----------------
__global__ __launch_bounds__(256)
void k_routing(const float* __restrict__ vec,
               const float* __restrict__ Wg, const float* __restrict__ bg,
               const float* __restrict__ Wf, const float* __restrict__ bfv,
               const float* __restrict__ wgt,
               float* __restrict__ c0, float* __restrict__ c1)
{
  const int wave = threadIdx.x >> 6;
  const int lane = threadIdx.x & 63;
  const int m = blockIdx.x * 4 + wave;
  const float* v = vec + (size_t)m * DDIM;

  float ag[NEXP], af[NEXP];
#pragma unroll
  for (int e = 0; e < NEXP; ++e) { ag[e] = 0.f; af[e] = 0.f; }

  for (int i = lane; i < HDIM; i += 64) {
    const float xg = v[i];
    const float xf = v[HDIM + i];
    const float4 wg0 = *(const float4*)(Wg + i * NEXP);
    const float4 wg1 = *(const float4*)(Wg + i * NEXP + 4);
    const float4 wf0 = *(const float4*)(Wf + i * NEXP);
    const float4 wf1 = *(const float4*)(Wf + i * NEXP + 4);
    ag[0] += xg * wg0.x; ag[1] += xg * wg0.y; ag[2] += xg * wg0.z; ag[3] += xg * wg0.w;
    ag[4] += xg * wg1.x; ag[5] += xg * wg1.y; ag[6] += xg * wg1.z; ag[7] += xg * wg1.w;
    af[0] += xf * wf0.x; af[1] += xf * wf0.y; af[2] += xf * wf0.z; af[3] += xf * wf0.w;
    af[4] += xf * wf1.x; af[5] += xf * wf1.y; af[6] += xf * wf1.z; af[7] += xf * wf1.w;
  }
#pragma unroll
  for (int e = 0; e < NEXP; ++e) {
#pragma unroll
    for (int off = 32; off >= 1; off >>= 1) {
      ag[e] += __shfl_xor(ag[e], off, 64);
      af[e] += __shfl_xor(af[e], off, 64);
    }
  }
  if (lane == 0) {
    float g[NEXP], f[NEXP];
    float mg = -1e30f, mf = -1e30f;
#pragma unroll
    for (int e = 0; e < NEXP; ++e) {
      g[e] = ag[e] + bg[e]; mg = fmaxf(mg, g[e]);
      f[e] = af[e] + bfv[e]; mf = fmaxf(mf, f[e]);
    }
    float sg = 0.f, sf = 0.f;
#pragma unroll
    for (int e = 0; e < NEXP; ++e) {
      g[e] = expf(g[e] - mg); sg += g[e];
      f[e] = expf(f[e] - mf); sf += f[e];
    }
    const float rg = 1.f / sg, rf = 1.f / sf;
#pragma unroll
    for (int e = 0; e < NEXP; ++e) { g[e] *= rg; f[e] *= rf; }
    int i1 = 0;
#pragma unroll
    for (int e = 1; e < NEXP; ++e) if (g[e] > g[i1]) i1 = e;
    int i2 = (i1 == 0) ? 1 : 0;
#pragma unroll
    for (int e = 0; e < NEXP; ++e) if (e != i1 && g[e] > g[i2]) i2 = e;
    const float w0 = wgt[0], w1 = wgt[1];
#pragma unroll
    for (int e = 0; e < NEXP; ++e) {
      c0[e * TOKENS + m] = (e == i1 || e == i2) ? w0 * g[e] : 0.f;
      c1[e * TOKENS + m] = w1 * f[e];
    }
  }
}

// ---------------- fp32 -> bf16 (X) ----------------
__global__ __launch_bounds__(256)
void k_cvt(const float* __restrict__ in, bf16_t* __restrict__ out)
{
  const size_t i = ((size_t)blockIdx.x * 256 + threadIdx.x) * 8;
  const float4 a = *(const float4*)(in + i);
  const float4 b = *(const float4*)(in + i + 4);
  bf16x8 o;
  o[0] = (bf16_t)a.x; o[1] = (bf16_t)a.y; o[2] = (bf16_t)a.z; o[3] = (bf16_t)a.w;
  o[4] = (bf16_t)b.x; o[5] = (bf16_t)b.y; o[6] = (bf16_t)b.z; o[7] = (bf16_t)b.w;
  *(bf16x8*)(out + i) = o;
}

// ---------------- fp32 W[k][n] -> bf16 Wt[n][k] (64x64 tile via LDS) ----------------
#define TP 68
__global__ __launch_bounds__(256)
void k_cvt_wt(const float* __restrict__ W, bf16_t* __restrict__ Wt)
{
  __shared__ __attribute__((aligned(16))) bf16_t tile[64 * TP];
  const size_t eoff = (size_t)blockIdx.z * DDIM * DDIM;
  const float* w = W + eoff;
  bf16_t* wt = Wt + eoff;
  const int k0 = blockIdx.x * 64;
  const int n0 = blockIdx.y * 64;
  const int t = threadIdx.x;
  const int c4 = (t & 15) * 4;
  const int rb = (t >> 4) * 4;
#pragma unroll
  for (int rr = 0; rr < 4; ++rr) {
    const int r = rb + rr;
    const float4 v = *(const float4*)(w + (size_t)(k0 + r) * DDIM + n0 + c4);
    tile[(c4 + 0) * TP + r] = (bf16_t)v.x;
    tile[(c4 + 1) * TP + r] = (bf16_t)v.y;
    tile[(c4 + 2) * TP + r] = (bf16_t)v.z;
    tile[(c4 + 3) * TP + r] = (bf16_t)v.w;
  }
  __syncthreads();
  const int nl = t >> 2;
  const int kq = (t & 3) * 16;
  bf16_t* dst = wt + (size_t)(n0 + nl) * DDIM + k0 + kq;
#pragma unroll
  for (int j2 = 0; j2 < 4; ++j2) {
    bf16x4 u = *(const bf16x4*)(&tile[nl * TP + kq + j2 * 4]);
    *(bf16x4*)(dst + j2 * 4) = u;
  }
}

// =====================================================================================
// Per-panel pipelined GEMM (T2 swizzle + T4 counted vmcnt + T5 setprio).
//   K panels of 32 cols; ring of 4 LDS units per matrix; 3 panels in flight.
//   Phase p: {ds_read frags(unit p&3) | stage panel p+3 | MFMA (compiler-staggered
//   lgkmcnt waits pipeline LDS vs matrix pipe) | vmcnt(F) | bar}
//   NOTE: no explicit lgkmcnt(0) drain -- plain C++ vector loads let the compiler
//   emit fine-grained waits so the first MFMA starts as soon as its operands land.
//   VMC's "memory" clobber pins all LDS reads inside their phase (ring WAR/RAW safe).
// =====================================================================================

// read a bf16x8 fragment: row R (swizzled), k-quad KQ within the 32-col panel
#define FRG(base, R, KQ) \
  (*(const bf16x8*)((base) + ((((R) * 32 + (KQ)) ^ ((((R) >> 3) & 1) << 4)))))

#define MFMA_(d, x, y) (d) = __builtin_amdgcn_mfma_f32_16x16x32_bf16((x), (y), (d), 0, 0, 0)

// ---------------- GEMM1 (all experts): hidden_e = relu(X @ W1_e + b1_e), bf16 ----------------
// 256x256 block, 8 waves (2Mx4N), wave tile 128x64. grid (16, 8, 8), 512 threads.
// LDS: A ring 4x16KiB + B ring 4x16KiB = 128 KiB. 4 gld_lds16 per panel -> vmcnt(8) steady.
__global__ __launch_bounds__(512, 2)
void k_gemm1_8p(const bf16_t* __restrict__ A, const bf16_t* __restrict__ W1t,
                const float* __restrict__ b1, bf16_t* __restrict__ Hd)
{
  __shared__ __attribute__((aligned(16))) bf16_t AsF[4 * 8192];
  __shared__ __attribute__((aligned(16))) bf16_t BsF[4 * 8192];
  const int e = blockIdx.z;
  const int t = threadIdx.x;
  const int wave = t >> 6, lane = t & 63;
  const int m0 = blockIdx.x * 256, n0 = blockIdx.y * 256;
  const int wm = (wave >> 2) * 128, wn = (wave & 3) * 64;
  const int fr = lane & 15, kq = (lane >> 4) * 8;

  // staging coords: linear LDS slot (wave,lane) -> inverse-swizzled global (row,col)
  const int sRw = wave * 16 + (lane >> 2);
  const int sC  = ((lane & 3) * 8) ^ (((lane >> 5) & 1) << 4);
  const bf16_t* aSrc = A + (size_t)(m0 + sRw) * GK + sC;
  const bf16_t* bSrc = W1t + (size_t)e * GN * GK + (size_t)(n0 + sRw) * GK + sC;
  bf16_t* aDst = AsF + wave * 512;
  bf16_t* bDst = BsF + wave * 512;

#define STA1(P, U) do { const bf16_t* _s = aSrc + (size_t)(P) * 32; \
    gld_lds16(_s, aDst + (U) * 8192); \
    gld_lds16(_s + (size_t)128 * GK, aDst + (U) * 8192 + 4096); } while (0)
#define STB1(P, U) do { const bf16_t* _s = bSrc + (size_t)(P) * 32; \
    gld_lds16(_s, bDst + (U) * 8192); \
    gld_lds16(_s + (size_t)128 * GK, bDst + (U) * 8192 + 4096); } while (0)

  f32x4 acc[8][4] = {};

#define PH1(U, SP, SU, DOST) do { \
    bf16x8 a_[8], b_[4]; \
    _Pragma("unroll") \
    for (int _j = 0; _j < 4; ++_j) b_[_j] = FRG(BsF + (U) * 8192, wn + _j * 16 + fr, kq); \
    _Pragma("unroll") \
    for (int _i = 0; _i < 8; ++_i) a_[_i] = FRG(AsF + (U) * 8192, wm + _i * 16 + fr, kq); \
    if (DOST) { STA1(SP, SU); STB1(SP, SU); } \
    __builtin_amdgcn_s_setprio(1); \
    _Pragma("unroll") \
    for (int _i = 0; _i < 8; ++_i) \
      _Pragma("unroll") \
      for (int _j = 0; _j < 4; ++_j) MFMA_(acc[_i][_j], a_[_i], b_[_j]); \
    __builtin_amdgcn_s_setprio(0); \
  } while (0)

  // prologue: panels 0..2 in flight (12 loads), drain panel 0
  STA1(0, 0); STB1(0, 0);
  STA1(1, 1); STB1(1, 1);
  STA1(2, 2); STB1(2, 2);
  VMC(8); BAR();

#pragma unroll 1
  for (int pb = 0; pb < 60; pb += 4) {
    PH1(0, pb + 3, 3, 1); VMC(8); BAR();
    PH1(1, pb + 4, 0, 1); VMC(8); BAR();
    PH1(2, pb + 5, 1, 1); VMC(8); BAR();
    PH1(3, pb + 6, 2, 1); VMC(8); BAR();
  }
  PH1(0, 63, 3, 1); VMC(8); BAR();
  PH1(1, 0, 0, 0);  VMC(4); BAR();
  PH1(2, 0, 0, 0);  VMC(0); BAR();
  PH1(3, 0, 0, 0);

  // epilogue: bias + relu -> bf16
  const float* bias = b1 + (size_t)e * DDIM;
  bf16_t* Hb = Hd + (size_t)e * TOKENS * DDIM;
  const int ecol = lane & 15, erow = (lane >> 4) * 4;
#pragma unroll
  for (int j = 0; j < 4; ++j) {
    const int gn = n0 + wn + j * 16 + ecol;
    const float bv = bias[gn];
#pragma unroll
    for (int i = 0; i < 8; ++i) {
      const int gm = m0 + wm + i * 16 + erow;
#pragma unroll
      for (int r = 0; r < 4; ++r) {
        float v = acc[i][j][r] + bv;
        v = v > 0.f ? v : 0.f;
        Hb[(size_t)(gm + r) * DDIM + gn] = (bf16_t)v;
      }
    }
  }
#undef PH1
#undef STA1
#undef STB1
}

// ---------------- GEMM2 (expert-summed): out = sum_e c_e[m] * (hidden_e @ W2_e + b2_e) ----------------
// 128x256 block, 8 waves (2Mx4N), wave tile 64x64. grid (32, 8), 512 threads (256 blocks = 1/CU).
// LDS: A ring 4x8KiB + B ring 4x16KiB = 96 KiB (+cs/bsh). 3 gld_lds16 per panel -> vmcnt(6) steady.
// 512 K-panels total (8 experts x 64); per-expert combine-fold at expert boundary.
__global__ __launch_bounds__(512, 2)
void k_gemm2_8p(const bf16_t* __restrict__ Hd, const bf16_t* __restrict__ W2t,
                const float* __restrict__ b2,
                const float* __restrict__ c0, const float* __restrict__ c1,
                float* __restrict__ out0, float* __restrict__ out1)
{
  __shared__ __attribute__((aligned(16))) bf16_t AsF[4 * 4096];
  __shared__ __attribute__((aligned(16))) bf16_t BsF[4 * 8192];
  __shared__ float cs[NEXP][128];    // combine coeff for this block's 128 rows, per expert
  __shared__ float bsh[NEXP][256];   // bias for this block's 256 cols, per expert

  const int t = threadIdx.x;
  const int wave = t >> 6, lane = t & 63;
  const int m0 = blockIdx.x * 128, n0 = blockIdx.y * 256;
  const int wm = (wave >> 2) * 64, wn = (wave & 3) * 64;
  const int fr = lane & 15, kq = (lane >> 4) * 8;
  const bool hi = (n0 >= HDIM);
  const float* cc = hi ? c1 : c0;

  for (int idx = t; idx < NEXP * 128; idx += 512) {
    const int ee = idx >> 7, r = idx & 127;
    cs[ee][r] = cc[ee * TOKENS + m0 + r];
  }
  for (int idx = t; idx < NEXP * 256; idx += 512) {
    const int ee = idx >> 8, r = idx & 255;
    bsh[ee][r] = b2[ee * DDIM + n0 + r];
  }
  __syncthreads();   // cs/bsh visible before first use; no staging in flight yet

  const int sRw = wave * 16 + (lane >> 2);
  const int sC  = ((lane & 3) * 8) ^ (((lane >> 5) & 1) << 4);
  const bf16_t* aSrc = Hd + (size_t)(m0 + sRw) * GK + sC;    // + e*TOKENS*GK + k
  const bf16_t* bSrc = W2t + (size_t)(n0 + sRw) * GK + sC;   // + e*GN*GK + k
  bf16_t* aDst = AsF + wave * 512;
  bf16_t* bDst = BsF + wave * 512;

#define STA2(P, U) do { \
    const bf16_t* _s = aSrc + (size_t)((P) >> 6) * ((size_t)TOKENS * GK) + (size_t)((P) & 63) * 32; \
    gld_lds16(_s, aDst + (U) * 4096); } while (0)
#define STB2(P, U) do { \
    const bf16_t* _s = bSrc + (size_t)((P) >> 6) * ((size_t)GN * GK) + (size_t)((P) & 63) * 32; \
    gld_lds16(_s, bDst + (U) * 8192); \
    gld_lds16(_s + (size_t)128 * GK, bDst + (U) * 8192 + 4096); } while (0)

  f32x4 acc[4][4] = {};
  f32x4 fin[4][4] = {};

#define PH2(U, SP, SU, DOST) do { \
    bf16x8 a_[4], b_[4]; \
    _Pragma("unroll") \
    for (int _j = 0; _j < 4; ++_j) b_[_j] = FRG(BsF + (U) * 8192, wn + _j * 16 + fr, kq); \
    _Pragma("unroll") \
    for (int _i = 0; _i < 4; ++_i) a_[_i] = FRG(AsF + (U) * 4096, wm + _i * 16 + fr, kq); \
    if (DOST) { STA2(SP, SU); STB2(SP, SU); } \
    __builtin_amdgcn_s_setprio(1); \
    _Pragma("unroll") \
    for (int _i = 0; _i < 4; ++_i) \
      _Pragma("unroll") \
      for (int _j = 0; _j < 4; ++_j) MFMA_(acc[_i][_j], a_[_i], b_[_j]); \
    __builtin_amdgcn_s_setprio(0); \
  } while (0)

  const int ecol = lane & 15, erow = (lane >> 4) * 4;

#define FOLD2(E) do { \
    _Pragma("unroll") \
    for (int _j = 0; _j < 4; ++_j) { \
      const float _bv = bsh[E][wn + _j * 16 + ecol]; \
      _Pragma("unroll") \
      for (int _i = 0; _i < 4; ++_i) { \
        const int _rw = wm + _i * 16 + erow; \
        _Pragma("unroll") \
        for (int _r = 0; _r < 4; ++_r) { \
          fin[_i][_j][_r] += cs[E][_rw + _r] * (acc[_i][_j][_r] + _bv); \
          acc[_i][_j][_r] = 0.f; \
        } \
      } \
    } \
  } while (0)

  // prologue: panels 0..2 in flight (9 loads), drain panel 0
  STA2(0, 0); STB2(0, 0);
  STA2(1, 1); STB2(1, 1);
  STA2(2, 2); STB2(2, 2);
  VMC(6); BAR();

#pragma unroll 1
  for (int pb = 0; pb < 508; pb += 4) {
    PH2(0, pb + 3, 3, 1); VMC(6); BAR();
    PH2(1, pb + 4, 0, 1); VMC(6); BAR();
    PH2(2, pb + 5, 1, 1); VMC(6); BAR();
    PH2(3, pb + 6, 2, 1);
    if ((pb & 63) == 60) FOLD2((pb + 3) >> 6);   // experts 0..6: after phase 64e+63
    VMC(6); BAR();
  }
  PH2(0, 511, 3, 1); VMC(6); BAR();   // phase 508, stages last panel
  PH2(1, 0, 0, 0);  VMC(3); BAR();    // phase 509
  PH2(2, 0, 0, 0);  VMC(0); BAR();    // phase 510
  PH2(3, 0, 0, 0);                    // phase 511
  FOLD2(7);

  // epilogue: write fp32 output exactly once
#pragma unroll
  for (int j = 0; j < 4; ++j) {
    const int gn = n0 + wn + j * 16 + ecol;
    float* ob = hi ? (out1 + (gn - HDIM)) : (out0 + gn);
#pragma unroll
    for (int i = 0; i < 4; ++i) {
      const int gm = m0 + wm + i * 16 + erow;
#pragma unroll
      for (int r = 0; r < 4; ++r)
        ob[(size_t)(gm + r) * HDIM] = fin[i][j][r];
    }
  }
#undef PH2
#undef STA2
#undef STB2
#undef FOLD2
}

// ---------------- legacy 128^2 kernels (small-ws fallback path) ----------------
__global__ __launch_bounds__(256, 2)
void k_gemm_relu(const bf16_t* __restrict__ A, const bf16_t* __restrict__ W1t,
                 const float* __restrict__ b1, bf16_t* __restrict__ Hd)
{
  __shared__ __attribute__((aligned(16))) bf16_t As[128 * 32];
  __shared__ __attribute__((aligned(16))) bf16_t Bs[128 * 32];
  const int e = blockIdx.z;
  const bf16_t* Bt = W1t + (size_t)e * GK * GN;
  const float* bias = b1 + (size_t)e * GN;
  bf16_t* H = Hd + (size_t)e * TOKENS * GN;

  const int t = threadIdx.x;
  const int wave = t >> 6;
  const int lane = t & 63;
  const int m0 = blockIdx.x * 128;
  const int n0 = blockIdx.y * 128;
  const int wm = (wave >> 1) << 6;
  const int wn = (wave & 1) << 6;

  f32x4 acc[4][4] = {};

  const bf16_t* aP0 = A + (size_t)(m0 + (t >> 2)) * GK + (t & 3) * 8;
  const bf16_t* aP1 = aP0 + (size_t)64 * GK;
  const bf16_t* bP0 = Bt + (size_t)(n0 + (t >> 2)) * GK + (t & 3) * 8;
  const bf16_t* bP1 = bP0 + (size_t)64 * GK;
  bf16_t* lA0 = As + wave * 512;
  bf16_t* lA1 = As + 2048 + wave * 512;
  bf16_t* lB0 = Bs + wave * 512;
  bf16_t* lB1 = Bs + 2048 + wave * 512;

  const int fr = lane & 15;
  const int kq = (lane >> 4) * 8;

  for (int k0 = 0; k0 < GK; k0 += 32) {
    gld_lds16(aP0 + k0, lA0);
    gld_lds16(aP1 + k0, lA1);
    gld_lds16(bP0 + k0, lB0);
    gld_lds16(bP1 + k0, lB1);
    __syncthreads();
    bf16x8 afr[4], bfr[4];
#pragma unroll
    for (int i = 0; i < 4; ++i) {
      afr[i] = *(const bf16x8*)(As + (wm + i * 16 + fr) * 32 + kq);
      bfr[i] = *(const bf16x8*)(Bs + (wn + i * 16 + fr) * 32 + kq);
    }
#pragma unroll
    for (int i = 0; i < 4; ++i)
#pragma unroll
      for (int j = 0; j < 4; ++j)
        acc[i][j] = __builtin_amdgcn_mfma_f32_16x16x32_bf16(afr[i], bfr[j], acc[i][j], 0, 0, 0);
    __syncthreads();
  }

  const int col = lane & 15;
  const int rq  = (lane >> 4) * 4;
#pragma unroll
  for (int j = 0; j < 4; ++j) {
    const int gn = n0 + wn + j * 16 + col;
    const float bv = bias[gn];
#pragma unroll
    for (int i = 0; i < 4; ++i) {
      const int gm = m0 + wm + i * 16 + rq;
#pragma unroll
      for (int r = 0; r < 4; ++r) {
        float v = acc[i][j][r] + bv;
        v = v > 0.f ? v : 0.f;
        H[(size_t)(gm + r) * GN + gn] = (bf16_t)v;
      }
    }
  }
}

__global__ __launch_bounds__(256, 2)
void k_gemm_out(const bf16_t* __restrict__ A, const bf16_t* __restrict__ Bt,
                const float* __restrict__ bias,
                const float* __restrict__ c0, const float* __restrict__ c1,
                float* __restrict__ out0, float* __restrict__ out1, const int accum)
{
  __shared__ __attribute__((aligned(16))) bf16_t As[128 * 32];
  __shared__ __attribute__((aligned(16))) bf16_t Bs[128 * 32];
  const int t = threadIdx.x;
  const int wave = t >> 6;
  const int lane = t & 63;
  const int m0 = blockIdx.x * 128;
  const int n0 = blockIdx.y * 128;
  const int wm = (wave >> 1) << 6;
  const int wn = (wave & 1) << 6;

  f32x4 acc[4][4] = {};

  const bf16_t* aP0 = A + (size_t)(m0 + (t >> 2)) * GK + (t & 3) * 8;
  const bf16_t* aP1 = aP0 + (size_t)64 * GK;
  const bf16_t* bP0 = Bt + (size_t)(n0 + (t >> 2)) * GK + (t & 3) * 8;
  const bf16_t* bP1 = bP0 + (size_t)64 * GK;
  bf16_t* lA0 = As + wave * 512;
  bf16_t* lA1 = As + 2048 + wave * 512;
  bf16_t* lB0 = Bs + wave * 512;
  bf16_t* lB1 = Bs + 2048 + wave * 512;

  const int fr = lane & 15;
  const int kq = (lane >> 4) * 8;

  for (int k0 = 0; k0 < GK; k0 += 32) {
    gld_lds16(aP0 + k0, lA0);
    gld_lds16(aP1 + k0, lA1);
    gld_lds16(bP0 + k0, lB0);
    gld_lds16(bP1 + k0, lB1);
    __syncthreads();
    bf16x8 afr[4], bfr[4];
#pragma unroll
    for (int i = 0; i < 4; ++i) {
      afr[i] = *(const bf16x8*)(As + (wm + i * 16 + fr) * 32 + kq);
      bfr[i] = *(const bf16x8*)(Bs + (wn + i * 16 + fr) * 32 + kq);
    }
#pragma unroll
    for (int i = 0; i < 4; ++i)
#pragma unroll
      for (int j = 0; j < 4; ++j)
        acc[i][j] = __builtin_amdgcn_mfma_f32_16x16x32_bf16(afr[i], bfr[j], acc[i][j], 0, 0, 0);
    __syncthreads();
  }

  const int col = lane & 15;
  const int rq  = (lane >> 4) * 4;
#pragma unroll
  for (int j = 0; j < 4; ++j) {
    const int gn = n0 + wn + j * 16 + col;
    const float bv = bias[gn];
    const bool lo = gn < HDIM;
    float* obase = lo ? (out0 + gn) : (out1 + (gn - HDIM));
    const float* cc = lo ? c0 : c1;
#pragma unroll
    for (int i = 0; i < 4; ++i) {
      const int gmB = m0 + wm + i * 16 + rq;
#pragma unroll
      for (int r = 0; r < 4; ++r) {
        const int gm = gmB + r;
        float v = (acc[i][j][r] + bv) * cc[gm];
        float* dst = obase + (size_t)gm * HDIM;
        if (accum) v += *dst;
        *dst = v;
      }
    }
  }
}

extern "C" void kernel_launch(void* const* d_in, const int* in_sizes, int n_in,
                              void* d_out, int out_size, void* d_ws, size_t ws_size,
                              hipStream_t stream)
{
  const float* vec = (const float*)d_in[0];
  const float* Wg  = (const float*)d_in[1];
  const float* bg  = (const float*)d_in[2];
  const float* Wf  = (const float*)d_in[3];
  const float* bfv = (const float*)d_in[4];
  const float* W1  = (const float*)d_in[5];
  const float* b1  = (const float*)d_in[6];
  const float* W2  = (const float*)d_in[7];
  const float* b2  = (const float*)d_in[8];
  const float* wgt = (const float*)d_in[9];

  float* out0 = (float*)d_out;
  float* out1 = out0 + (size_t)TOKENS * HDIM;

  char* base = (char*)d_ws;
  const size_t XB = (size_t)TOKENS * DDIM * 2;        // 16 MiB
  const size_t HB = (size_t)NEXP * TOKENS * DDIM * 2; // 128 MiB
  const size_t WT = (size_t)NEXP * DDIM * DDIM * 2;   // 64 MiB each

  bf16_t* Xbf = (bf16_t*)base;
  float*  c0  = (float*)(base + XB);
  float*  c1  = c0 + (size_t)NEXP * TOKENS;
  size_t off = XB + 2 * (size_t)NEXP * TOKENS * 4;

  k_routing<<<dim3(TOKENS / 4), 256, 0, stream>>>(vec, Wg, bg, Wf, bfv, wgt, c0, c1);
  k_cvt<<<dim3((TOKENS * DDIM) / 2048), 256, 0, stream>>>(vec, Xbf);

  if (ws_size >= off + HB + 2 * WT) {
    // big path: per-expert hidden + both weight tensors pre-converted, pipelined GEMMs
    bf16_t* hidden = (bf16_t*)(base + off);
    bf16_t* W1t    = (bf16_t*)(base + off + HB);
    bf16_t* W2t    = (bf16_t*)(base + off + HB + WT);
    k_cvt_wt<<<dim3(32, 32, NEXP), 256, 0, stream>>>(W1, W1t);
    k_cvt_wt<<<dim3(32, 32, NEXP), 256, 0, stream>>>(W2, W2t);
    k_gemm1_8p<<<dim3(16, 8, NEXP), 512, 0, stream>>>(Xbf, W1t, b1, hidden);
    k_gemm2_8p<<<dim3(32, 8), 512, 0, stream>>>(hidden, W2t, b2, c0, c1, out0, out1);
  } else {
    // small-ws fallback: sequential per-expert with reused buffers (legacy kernels)
    bf16_t* hidden = (bf16_t*)(base + off);
    bf16_t* W1t    = hidden + (size_t)TOKENS * DDIM;
    bf16_t* W2t    = W1t + (size_t)DDIM * DDIM;
    for (int e = 0; e < NEXP; ++e) {
      k_cvt_wt<<<dim3(32, 32, 1), 256, 0, stream>>>(W1 + (size_t)e * DDIM * DDIM, W1t);
      k_cvt_wt<<<dim3(32, 32, 1), 256, 0, stream>>>(W2 + (size_t)e * DDIM * DDIM, W2t);
      k_gemm_relu<<<dim3(32, 16, 1), 256, 0, stream>>>(Xbf, W1t, b1 + (size_t)e * DDIM, hidden);
      k_gemm_out<<<dim3(32, 16), 256, 0, stream>>>(
          hidden, W2t, b2 + (size_t)e * DDIM,
          c0 + (size_t)e * TOKENS, c1 + (size_t)e * TOKENS, out0, out1, e > 0);
    }
  }
}